// Round 15
// baseline (120.331 us; speedup 1.0000x reference)
//
#include <hip/hip_runtime.h>

#define B_ 2
#define S_ 2048
#define D_ 1024
#define H_ 16

typedef __attribute__((ext_vector_type(8))) short short8;
typedef __attribute__((ext_vector_type(8))) unsigned short ushort8;
typedef __attribute__((ext_vector_type(4))) short short4v;
typedef __attribute__((ext_vector_type(4))) float f32x4;

__device__ __forceinline__ unsigned short f2b(float f){
  unsigned u = __float_as_uint(f);
  u += 0x7fffu + ((u >> 16) & 1u);
  return (unsigned short)(u >> 16);
}
__device__ __forceinline__ float b2f(unsigned short b){
  return __uint_as_float(((unsigned)b) << 16);
}
__device__ __forceinline__ float fast_exp2(float x){
#if __has_builtin(__builtin_amdgcn_exp2f)
  return __builtin_amdgcn_exp2f(x);
#else
  return exp2f(x);
#endif
}
__device__ __forceinline__ unsigned pack_trunc(unsigned u_lo, unsigned u_hi){
#if __has_builtin(__builtin_amdgcn_perm)
  return __builtin_amdgcn_perm(u_hi, u_lo, 0x07060302u);
#else
  return (u_lo >> 16) | (u_hi & 0xffff0000u);
#endif
}
__device__ __forceinline__ f32x4 mfma16(short8 a, short8 b, f32x4 c){
  return __builtin_amdgcn_mfma_f32_16x16x32_bf16(a, b, c, 0, 0, 0);
}
__device__ __forceinline__ f32x4 mfma16k16(short4v a, short4v b, f32x4 c){
#if __has_builtin(__builtin_amdgcn_mfma_f32_16x16x16bf16_1k)
  return __builtin_amdgcn_mfma_f32_16x16x16bf16_1k(a, b, c, 0, 0, 0);
#else
  asm("v_mfma_f32_16x16x16_bf16 %0, %1, %2, %0" : "+v"(c) : "v"(a), "v"(b));
  return c;
#endif
}
__device__ __forceinline__ void gload_lds16(const void* g, void* l){
  __builtin_amdgcn_global_load_lds((const __attribute__((address_space(1))) unsigned int*)g,
                                   (__attribute__((address_space(3))) unsigned int*)l, 16, 0, 0);
}

// ---- kernel 1: fused prep -------------------------------------------------
__global__ __launch_bounds__(256) void prep(const float* __restrict__ x,
                                            const float* __restrict__ Wq,
                                            const float* __restrict__ Wk,
                                            const float* __restrict__ Wv,
                                            unsigned short* __restrict__ xbf,
                                            unsigned short* __restrict__ wT){
  const int z = blockIdx.z;
  if (z == 3){
    int lb = blockIdx.y * 32 + blockIdx.x;
    int i = (lb * 256 + threadIdx.x) * 16;
    #pragma unroll
    for (int half = 0; half < 2; half++){
      f32x4 a = *(const f32x4*)(x + i + half * 8);
      f32x4 b = *(const f32x4*)(x + i + half * 8 + 4);
      ushort8 o;
      o[0]=f2b(a[0]); o[1]=f2b(a[1]); o[2]=f2b(a[2]); o[3]=f2b(a[3]);
      o[4]=f2b(b[0]); o[5]=f2b(b[1]); o[6]=f2b(b[2]); o[7]=f2b(b[3]);
      *(ushort8*)(xbf + i + half * 8) = o;
    }
    return;
  }
  const float* W = (z == 0) ? Wq : ((z == 1) ? Wk : Wv);
  __shared__ float tile[32][33];
  int nb = blockIdx.x * 32, kb = blockIdx.y * 32;
  int tx = threadIdx.x & 31, ty = threadIdx.x >> 5;
  #pragma unroll
  for (int it = 0; it < 4; it++){
    int row = ty + it * 8;
    tile[row][tx] = W[(size_t)(kb + row) * D_ + nb + tx];
  }
  __syncthreads();
  unsigned short* outp = wT + (size_t)z * D_ * D_;
  #pragma unroll
  for (int it = 0; it < 4; it++){
    int row = ty + it * 8;
    int n = nb + row;
    int np = ((n & 15) << 6) | (n >> 4);
    outp[(size_t)np * D_ + kb + tx] = f2b(tile[tx][row]);
  }
}

// ---- kernel 3: QKV projection GEMM (unchanged, round-13-proven) ----------
__global__ __launch_bounds__(256) void qkv_gemm(const unsigned short* __restrict__ xbf,
                                                const unsigned short* __restrict__ wT,
                                                const float* __restrict__ Bq,
                                                unsigned short* __restrict__ qatt,
                                                unsigned short* __restrict__ katt,
                                                unsigned short* __restrict__ vatt){
  __shared__ char SM[34816];
  unsigned short* Ct = (unsigned short*)SM;
  const int proj = blockIdx.z;
  const int mbase = blockIdx.y * 128, nbase = blockIdx.x * 128;
  const unsigned short* bsrc = wT + (size_t)proj * D_ * D_;
  const int t = threadIdx.x, w = t >> 6, lane = t & 63, ln = lane & 15, hi = lane >> 4;
  const int wr = w >> 1, wc = w & 1;
  const int srow = t >> 2, scol = (t & 3) << 3;
  f32x4 acc[4][4] = {};

  #pragma unroll
  for (int i = 0; i < 2; i++){
    gload_lds16(xbf  + (size_t)(mbase + srow + i * 64) * D_ + scol, SM + w * 1024 + i * 4096);
    gload_lds16(bsrc + (size_t)(nbase + srow + i * 64) * D_ + scol, SM + 8192 + w * 1024 + i * 4096);
  }
  __syncthreads();

  int cur = 0;
  for (int ks = 0; ks < D_; ks += 32){
    if (ks + 32 < D_){
      char* nb_ = SM + (cur ^ 1) * 16384;
      #pragma unroll
      for (int i = 0; i < 2; i++){
        gload_lds16(xbf  + (size_t)(mbase + srow + i * 64) * D_ + ks + 32 + scol, nb_ + w * 1024 + i * 4096);
        gload_lds16(bsrc + (size_t)(nbase + srow + i * 64) * D_ + ks + 32 + scol, nb_ + 8192 + w * 1024 + i * 4096);
      }
    }
    const unsigned short* At = (const unsigned short*)(SM + cur * 16384);
    const unsigned short* Bt = (const unsigned short*)(SM + cur * 16384 + 8192);
    short8 af[4], bf[4];
    #pragma unroll
    for (int q = 0; q < 4; q++) af[q] = *(const short8*)&At[(wr * 64 + q * 16 + ln) * 32 + hi * 8];
    #pragma unroll
    for (int p = 0; p < 4; p++) bf[p] = *(const short8*)&Bt[(wc * 64 + p * 16 + ln) * 32 + hi * 8];
    #pragma unroll
    for (int q = 0; q < 4; q++)
      #pragma unroll
      for (int p = 0; p < 4; p++)
        acc[q][p] = mfma16(af[q], bf[p], acc[q][p]);
    __syncthreads();
    cur ^= 1;
  }

  const float qscale = 0.04508422002778011f; // log2(e)/sqrt(1024)
  const int b = mbase >> 11, ms = mbase & 2047;

  if (proj == 2){
    #pragma unroll
    for (int p = 0; p < 4; p++)
      #pragma unroll
      for (int q = 0; q < 4; q++)
        #pragma unroll
        for (int r = 0; r < 4; r++)
          Ct[(wc*64 + p*16 + ln) * 136 + wr*64 + q*16 + hi*4 + r] = f2b(acc[q][p][r]);
    __syncthreads();
    #pragma unroll
    for (int j = 0; j < 8; j++){
      int u = j * 256 + t;
      int col = u >> 4, s0 = (u & 15) * 8;
      int h = blockIdx.x * 2 + (col >> 6), r = col & 63;
      short8 v = *(const short8*)&Ct[col * 136 + s0];
      *(short8*)&vatt[((size_t)(b*16 + h) * 64 + r) * 2048 + ms + s0] = v;
    }
  } else {
    const int hglob = blockIdx.x * 2 + wc;
    #pragma unroll
    for (int p = 0; p < 4; p++){
      float bqv = (proj == 0) ? Bq[(p*16 + ln)*16 + hglob] : 0.f;
      #pragma unroll
      for (int q = 0; q < 4; q++)
        #pragma unroll
        for (int r = 0; r < 4; r++){
          float v = acc[q][p][r];
          if (proj == 0) v = (v + bqv) * qscale;
          Ct[(wr*64 + q*16 + hi*4 + r) * 136 + wc*64 + p*16 + ln] = f2b(v);
        }
    }
    __syncthreads();
    unsigned short* dstb = (proj == 0) ? qatt : katt;
    #pragma unroll
    for (int j = 0; j < 8; j++){
      int u = j * 256 + t;
      int hl = u >> 10, rem = u & 1023, sl = rem >> 3, r0 = (rem & 7) * 8;
      int h = blockIdx.x * 2 + hl;
      short8 v = *(const short8*)&Ct[sl * 136 + hl*64 + r0];
      *(short8*)&dstb[((size_t)(b*16 + h) * 2048 + ms + sl) * 64 + r0] = v;
    }
  }
}

// ---- kernel 4: attention — 1-wave self-paced blocks, ZERO barriers -------
// Each 64-thread block = one wave; stages its own 64x64 K/V tile; counted
// intra-wave s_waitcnt only (vmcnt(8) for K, vmcnt(0) for V, lgkmcnt(0) at
// loop end before the buffer is overwritten). 16KB LDS -> 10 blocks/CU,
// all waves independent and phase-staggered.
template<int NS>
__global__ __launch_bounds__(64) void attn_fwd(const unsigned short* __restrict__ qatt,
                                               const unsigned short* __restrict__ katt,
                                               const unsigned short* __restrict__ vatt,
                                               unsigned short* __restrict__ pnum,
                                               float* __restrict__ pden){
  __shared__ unsigned short Kt[64 * 64];
  __shared__ unsigned short Vt[64 * 64];
  const int lane = threadIdx.x & 63, ln = lane & 15, hi = lane >> 4;
  const int bid = blockIdx.x;                 // grid = 2048*NS
  const int bpx = (2048 * NS) / 8;
  const int L = (bid & 7) * bpx + (bid >> 3); // bijective XCD swizzle
  const int bh = L / (64 * NS);
  const int rem = L % (64 * NS);
  const int z = rem >> 6, qc = rem & 63;
  const int b = bh >> 4, h = bh & 15;
  const int q0 = qc * 32;
  const int kvbase = z * (S_ / NS);
  const int NT = (S_ / NS) / 64;
  const unsigned short* Qh = qatt + (size_t)bh * S_ * 64;
  const unsigned short* Kh = katt + (size_t)bh * S_ * 64;
  const unsigned short* Vh = vatt + (size_t)bh * 64 * S_;

  short8 qf[2][2];
  #pragma unroll
  for (int qb = 0; qb < 2; qb++)
    #pragma unroll
    for (int kc = 0; kc < 2; kc++)
      qf[qb][kc] = *(const short8*)&Qh[(size_t)(q0 + qb * 16 + ln) * 64 + kc * 32 + hi * 8];

  // staging: instr i covers rows i*8+(lane>>3); col chunk (lane&7)*16B ^ swz
  const int srow8 = lane >> 3;
  const int scolX = ((lane & 7) << 4) ^ (srow8 << 4);   // (row&7)==srow8 for all i

  f32x4 acc[2][4] = {};
  f32x4 accd[2] = {};
  const short4v vones = {(short)0x3F80, (short)0x3F80, (short)0x3F80, (short)0x3F80};

  for (int tt = 0; tt < NT; ++tt){
    const int kv = kvbase + tt * 64;
    #pragma unroll
    for (int i = 0; i < 8; i++)
      gload_lds16(Kh + (size_t)(kv + i * 8 + srow8) * 64 + (scolX >> 1), (char*)Kt + i * 1024);
    #pragma unroll
    for (int i = 0; i < 8; i++)
      gload_lds16(Vh + (size_t)(i * 8 + srow8) * S_ + kv + (scolX >> 1), (char*)Vt + i * 1024);

    asm volatile("s_waitcnt vmcnt(8)" ::: "memory");   // K tile landed (V still in flight)
    __builtin_amdgcn_s_setprio(1);

    short8 kf[4][2];
    #pragma unroll
    for (int kb = 0; kb < 4; kb++)
      #pragma unroll
      for (int kc = 0; kc < 2; kc++){
        int eb = (((kc * 64 + hi * 16) ^ ((ln & 7) << 4)) >> 1);
        kf[kb][kc] = *(const short8*)&Kt[(kb * 16 + ln) * 64 + eb];
      }

    short4v pa[2][4];
    #pragma unroll
    for (int qb = 0; qb < 2; qb++)
      #pragma unroll
      for (int kb = 0; kb < 4; kb++){
        f32x4 zz = {0.f, 0.f, 0.f, 0.f};
        zz = mfma16(kf[kb][0], qf[qb][0], zz);
        zz = mfma16(kf[kb][1], qf[qb][1], zz);
        unsigned u0 = __float_as_uint(fast_exp2(zz[0]));
        unsigned u1 = __float_as_uint(fast_exp2(zz[1]));
        unsigned u2 = __float_as_uint(fast_exp2(zz[2]));
        unsigned u3 = __float_as_uint(fast_exp2(zz[3]));
        union { unsigned u[2]; short4v s; } pk;
        pk.u[0] = pack_trunc(u0, u1);
        pk.u[1] = pack_trunc(u2, u3);
        pa[qb][kb] = pk.s;
      }

    // denominator on the matrix pipe (same truncated addends as numerator)
    #pragma unroll
    for (int kb = 0; kb < 4; kb++){
      accd[0] = mfma16k16(pa[0][kb], vones, accd[0]);
      accd[1] = mfma16k16(pa[1][kb], vones, accd[1]);
    }

    asm volatile("s_waitcnt vmcnt(0)" ::: "memory");   // V tile landed
    #pragma unroll
    for (int cb = 0; cb < 4; cb++)
      #pragma unroll
      for (int kb = 0; kb < 4; kb++){
        int eb = (((kb * 32 + hi * 8) ^ ((ln & 7) << 4)) >> 1);
        short4v vf = *(const short4v*)&Vt[(cb * 16 + ln) * 64 + eb];
        acc[0][cb] = mfma16k16(pa[0][kb], vf, acc[0][cb]);
        acc[1][cb] = mfma16k16(pa[1][kb], vf, acc[1][cb]);
      }
    __builtin_amdgcn_s_setprio(0);
    asm volatile("s_waitcnt lgkmcnt(0)" ::: "memory"); // all ds_reads done before overwrite
  }

  if (ln == 0){
    #pragma unroll
    for (int qb = 0; qb < 2; qb++)
      #pragma unroll
      for (int r = 0; r < 4; r++)
        pden[((size_t)(z * 2 + b) * S_ + q0 + qb * 16 + hi * 4 + r) * 16 + h] = accd[qb][r];
  }

  const size_t rowb = (size_t)(z * 2 + b) * S_;
  #pragma unroll
  for (int qb = 0; qb < 2; qb++)
    #pragma unroll
    for (int cb = 0; cb < 4; cb++)
      #pragma unroll
      for (int r = 0; r < 4; r++){
        int qrow = q0 + qb * 16 + hi * 4 + r;
        pnum[(rowb + qrow) * 1024 + h * 64 + cb * 16 + ln] = f2b(acc[qb][cb][r]);
      }
}

// ---- kernel 5: combine partials (h-major), transpose, normalize ----------
template<int NSPLIT>
__global__ __launch_bounds__(256) void attn_reduce(const unsigned short* __restrict__ pnum,
                                                   const float* __restrict__ pden,
                                                   float* __restrict__ out){
  __shared__ float L[4 * 1056];
  const int t = threadIdx.x;
  const int row_l = t >> 6, lane = t & 63;
  const int grow = blockIdx.x * 4 + row_l;
  const int e0 = lane * 16;
  const int h = e0 >> 6;
  float den = 0.f;
  float nsum[16];
  #pragma unroll
  for (int j = 0; j < 16; j++) nsum[j] = 0.f;
  #pragma unroll
  for (int z = 0; z < NSPLIT; z++){
    const size_t prow = (size_t)z * 4096 + grow;
    den += pden[prow * 16 + h];
    #pragma unroll
    for (int c = 0; c < 2; c++){
      ushort8 nv = *(const ushort8*)&pnum[prow * 1024 + e0 + c * 8];
      #pragma unroll
      for (int k = 0; k < 8; k++) nsum[c*8 + k] += b2f(nv[k]);
    }
  }
  float rinv = 1.0f / den;
  #pragma unroll
  for (int j = 0; j < 16; j++){
    int col = e0 + j;
    L[row_l * 1056 + col + (col >> 5)] = nsum[j] * rinv;
  }
  __syncthreads();
  const int d0 = lane * 16;
  #pragma unroll
  for (int c = 0; c < 4; c++){
    f32x4 o;
    #pragma unroll
    for (int k = 0; k < 4; k++){
      int d = d0 + c * 4 + k;
      int e = ((d & 15) << 6) | (d >> 4);
      o[k] = L[row_l * 1056 + e + (e >> 5)];
    }
    *(f32x4*)&out[(size_t)grow * 1024 + d0 + c * 4] = o;
  }
}

extern "C" void kernel_launch(void* const* d_in, const int* in_sizes, int n_in,
                              void* d_out, int out_size, void* d_ws, size_t ws_size,
                              hipStream_t stream){
  const float* x  = (const float*)d_in[0];
  const float* Wq = (const float*)d_in[1];
  const float* Bq = (const float*)d_in[2];
  const float* Wk = (const float*)d_in[3];
  const float* Wv = (const float*)d_in[4];
  char* ws = (char*)d_ws;
  const size_t MB = 1024 * 1024;
  unsigned short* qatt = (unsigned short*)(ws);
  unsigned short* katt = (unsigned short*)(ws + 8 * MB);
  unsigned short* vatt = (unsigned short*)(ws + 16 * MB);
  unsigned short* xbf  = (unsigned short*)(ws + 24 * MB);
  unsigned short* wT   = (unsigned short*)(ws + 32 * MB);
  float* outp = (float*)d_out;

  prep<<<dim3(32, 32, 4), 256, 0, stream>>>(x, Wq, Wk, Wv, xbf, wT);
  qkv_gemm<<<dim3(8, 32, 3), 256, 0, stream>>>(xbf, wT, Bq, qatt, katt, vatt);

  if (ws_size >= 59 * MB){
    const int NS = 4;
    unsigned short* pnum = (unsigned short*)(ws + 24 * MB);
    float* pden = (float*)(ws + 24 * MB + (size_t)NS * 8 * MB);
    attn_fwd<NS><<<2048 * NS, 64, 0, stream>>>(qatt, katt, vatt, pnum, pden);
    attn_reduce<NS><<<1024, 256, 0, stream>>>(pnum, pden, outp);
  } else if (ws_size >= 42 * MB){
    const int NS = 2;
    unsigned short* pnum = (unsigned short*)(ws + 24 * MB);
    float* pden = (float*)(ws + 24 * MB + (size_t)NS * 8 * MB);
    attn_fwd<NS><<<2048 * NS, 64, 0, stream>>>(qatt, katt, vatt, pnum, pden);
    attn_reduce<NS><<<1024, 256, 0, stream>>>(pnum, pden, outp);
  } else {
    const int NS = 1;
    unsigned short* pnum = (unsigned short*)(ws + 24 * MB);
    float* pden = (float*)(ws + 24 * MB + (size_t)NS * 8 * MB);
    attn_fwd<NS><<<2048 * NS, 64, 0, stream>>>(qatt, katt, vatt, pnum, pden);
    attn_reduce<NS><<<1024, 256, 0, stream>>>(pnum, pden, outp);
  }
}

// Round 16
// 99.996 us; speedup vs baseline: 1.2034x; 1.2034x over previous
//
#include <hip/hip_runtime.h>

#define B_ 2
#define S_ 2048
#define D_ 1024
#define H_ 16

typedef __attribute__((ext_vector_type(8))) short short8;
typedef __attribute__((ext_vector_type(8))) unsigned short ushort8;
typedef __attribute__((ext_vector_type(4))) short short4v;
typedef __attribute__((ext_vector_type(4))) float f32x4;

__device__ __forceinline__ unsigned short f2b(float f){
  unsigned u = __float_as_uint(f);
  u += 0x7fffu + ((u >> 16) & 1u);
  return (unsigned short)(u >> 16);
}
__device__ __forceinline__ float b2f(unsigned short b){
  return __uint_as_float(((unsigned)b) << 16);
}
__device__ __forceinline__ float fast_exp2(float x){
#if __has_builtin(__builtin_amdgcn_exp2f)
  return __builtin_amdgcn_exp2f(x);
#else
  return exp2f(x);
#endif
}
__device__ __forceinline__ unsigned pack_trunc(unsigned u_lo, unsigned u_hi){
  // dst = {hi16(u_hi), hi16(u_lo)} : bf16-truncate two f32 and pack, 1 inst
#if __has_builtin(__builtin_amdgcn_perm)
  return __builtin_amdgcn_perm(u_hi, u_lo, 0x07060302u);
#else
  return (u_lo >> 16) | (u_hi & 0xffff0000u);
#endif
}
__device__ __forceinline__ f32x4 mfma16(short8 a, short8 b, f32x4 c){
  return __builtin_amdgcn_mfma_f32_16x16x32_bf16(a, b, c, 0, 0, 0);
}
__device__ __forceinline__ void gload_lds16(const void* g, void* l){
  __builtin_amdgcn_global_load_lds((const __attribute__((address_space(1))) unsigned int*)g,
                                   (__attribute__((address_space(3))) unsigned int*)l, 16, 0, 0);
}

// ---- kernel 1: fused prep -------------------------------------------------
__global__ __launch_bounds__(256) void prep(const float* __restrict__ x,
                                            const float* __restrict__ Wq,
                                            const float* __restrict__ Wk,
                                            const float* __restrict__ Wv,
                                            unsigned short* __restrict__ xbf,
                                            unsigned short* __restrict__ wT){
  const int z = blockIdx.z;
  if (z == 3){
    int lb = blockIdx.y * 32 + blockIdx.x;
    int i = (lb * 256 + threadIdx.x) * 16;
    #pragma unroll
    for (int half = 0; half < 2; half++){
      f32x4 a = *(const f32x4*)(x + i + half * 8);
      f32x4 b = *(const f32x4*)(x + i + half * 8 + 4);
      ushort8 o;
      o[0]=f2b(a[0]); o[1]=f2b(a[1]); o[2]=f2b(a[2]); o[3]=f2b(a[3]);
      o[4]=f2b(b[0]); o[5]=f2b(b[1]); o[6]=f2b(b[2]); o[7]=f2b(b[3]);
      *(ushort8*)(xbf + i + half * 8) = o;
    }
    return;
  }
  const float* W = (z == 0) ? Wq : ((z == 1) ? Wk : Wv);
  __shared__ float tile[32][33];
  int nb = blockIdx.x * 32, kb = blockIdx.y * 32;
  int tx = threadIdx.x & 31, ty = threadIdx.x >> 5;
  #pragma unroll
  for (int it = 0; it < 4; it++){
    int row = ty + it * 8;
    tile[row][tx] = W[(size_t)(kb + row) * D_ + nb + tx];
  }
  __syncthreads();
  unsigned short* outp = wT + (size_t)z * D_ * D_;
  #pragma unroll
  for (int it = 0; it < 4; it++){
    int row = ty + it * 8;
    int n = nb + row;
    int np = ((n & 15) << 6) | (n >> 4);
    outp[(size_t)np * D_ + kb + tx] = f2b(tile[tx][row]);
  }
}

// ---- kernel 3: QKV projection GEMM (round-13-proven) ----------------------
__global__ __launch_bounds__(256) void qkv_gemm(const unsigned short* __restrict__ xbf,
                                                const unsigned short* __restrict__ wT,
                                                const float* __restrict__ Bq,
                                                unsigned short* __restrict__ qatt,
                                                unsigned short* __restrict__ katt,
                                                unsigned short* __restrict__ vatt){
  __shared__ char SM[34816];
  unsigned short* Ct = (unsigned short*)SM;
  const int proj = blockIdx.z;
  const int mbase = blockIdx.y * 128, nbase = blockIdx.x * 128;
  const unsigned short* bsrc = wT + (size_t)proj * D_ * D_;
  const int t = threadIdx.x, w = t >> 6, lane = t & 63, ln = lane & 15, hi = lane >> 4;
  const int wr = w >> 1, wc = w & 1;
  const int srow = t >> 2, scol = (t & 3) << 3;
  f32x4 acc[4][4] = {};

  #pragma unroll
  for (int i = 0; i < 2; i++){
    gload_lds16(xbf  + (size_t)(mbase + srow + i * 64) * D_ + scol, SM + w * 1024 + i * 4096);
    gload_lds16(bsrc + (size_t)(nbase + srow + i * 64) * D_ + scol, SM + 8192 + w * 1024 + i * 4096);
  }
  __syncthreads();

  int cur = 0;
  for (int ks = 0; ks < D_; ks += 32){
    if (ks + 32 < D_){
      char* nb_ = SM + (cur ^ 1) * 16384;
      #pragma unroll
      for (int i = 0; i < 2; i++){
        gload_lds16(xbf  + (size_t)(mbase + srow + i * 64) * D_ + ks + 32 + scol, nb_ + w * 1024 + i * 4096);
        gload_lds16(bsrc + (size_t)(nbase + srow + i * 64) * D_ + ks + 32 + scol, nb_ + 8192 + w * 1024 + i * 4096);
      }
    }
    const unsigned short* At = (const unsigned short*)(SM + cur * 16384);
    const unsigned short* Bt = (const unsigned short*)(SM + cur * 16384 + 8192);
    short8 af[4], bf[4];
    #pragma unroll
    for (int q = 0; q < 4; q++) af[q] = *(const short8*)&At[(wr * 64 + q * 16 + ln) * 32 + hi * 8];
    #pragma unroll
    for (int p = 0; p < 4; p++) bf[p] = *(const short8*)&Bt[(wc * 64 + p * 16 + ln) * 32 + hi * 8];
    #pragma unroll
    for (int q = 0; q < 4; q++)
      #pragma unroll
      for (int p = 0; p < 4; p++)
        acc[q][p] = mfma16(af[q], bf[p], acc[q][p]);
    __syncthreads();
    cur ^= 1;
  }

  const float qscale = 0.04508422002778011f; // log2(e)/sqrt(1024)
  const int b = mbase >> 11, ms = mbase & 2047;

  if (proj == 2){
    #pragma unroll
    for (int p = 0; p < 4; p++)
      #pragma unroll
      for (int q = 0; q < 4; q++)
        #pragma unroll
        for (int r = 0; r < 4; r++)
          Ct[(wc*64 + p*16 + ln) * 136 + wr*64 + q*16 + hi*4 + r] = f2b(acc[q][p][r]);
    __syncthreads();
    #pragma unroll
    for (int j = 0; j < 8; j++){
      int u = j * 256 + t;
      int col = u >> 4, s0 = (u & 15) * 8;
      int h = blockIdx.x * 2 + (col >> 6), r = col & 63;
      short8 v = *(const short8*)&Ct[col * 136 + s0];
      *(short8*)&vatt[((size_t)(b*16 + h) * 64 + r) * 2048 + ms + s0] = v;
    }
  } else {
    const int hglob = blockIdx.x * 2 + wc;
    #pragma unroll
    for (int p = 0; p < 4; p++){
      float bqv = (proj == 0) ? Bq[(p*16 + ln)*16 + hglob] : 0.f;
      #pragma unroll
      for (int q = 0; q < 4; q++)
        #pragma unroll
        for (int r = 0; r < 4; r++){
          float v = acc[q][p][r];
          if (proj == 0) v = (v + bqv) * qscale;
          Ct[(wr*64 + q*16 + hi*4 + r) * 136 + wc*64 + p*16 + ln] = f2b(v);
        }
    }
    __syncthreads();
    unsigned short* dstb = (proj == 0) ? qatt : katt;
    #pragma unroll
    for (int j = 0; j < 8; j++){
      int u = j * 256 + t;
      int hl = u >> 10, rem = u & 1023, sl = rem >> 3, r0 = (rem & 7) * 8;
      int h = blockIdx.x * 2 + hl;
      short8 v = *(const short8*)&Ct[sl * 136 + hl*64 + r0];
      *(short8*)&dstb[((size_t)(b*16 + h) * 2048 + ms + sl) * 64 + r0] = v;
    }
  }
}

// ---- kernel 4: attention (round-13 base + K=32 PV via key-permuted K tile)
// K-tile rows are staged in bit-permuted key order p(t)=t5*32+t32*8+t4*4+t10,
// so the packed P words [a0,a1|a2,a3|b0,b1|b2,b3] form a valid 16x16x32
// A-fragment over NATURALLY-ordered keys; V tile + softmax sum unchanged
// (key order is summed out). PV: 32 K=16 MFMAs -> 16 K=32; denom: 8 -> 4.
template<int NS>
__global__ __launch_bounds__(256) void attn_fwd(const unsigned short* __restrict__ qatt,
                                                const unsigned short* __restrict__ katt,
                                                const unsigned short* __restrict__ vatt,
                                                unsigned short* __restrict__ pnum,
                                                float* __restrict__ pden){
  __shared__ unsigned short Kt[2][64 * 64];
  __shared__ unsigned short Vt[2][64 * 64];
  const int t = threadIdx.x, w = t >> 6, lane = t & 63, ln = lane & 15, hi = lane >> 4;
  const int bid = blockIdx.x;
  const int bpx = (512 * NS) / 8;
  const int L = (bid & 7) * bpx + (bid >> 3);
  const int bh = L / (16 * NS);
  const int rem = L % (16 * NS);
  const int z = rem >> 4, qc = rem & 15;
  const int b = bh >> 4, h = bh & 15;
  const int q0 = qc * 128 + w * 32;
  const int kvbase = z * (S_ / NS);
  const int NT = (S_ / NS) / 64;
  const unsigned short* Qh = qatt + (size_t)bh * S_ * 64;
  const unsigned short* Kh = katt + (size_t)bh * S_ * 64;
  const unsigned short* Vh = vatt + (size_t)bh * 64 * S_;

  short8 qf[2][2];
  #pragma unroll
  for (int qb = 0; qb < 2; qb++)
    #pragma unroll
    for (int kc = 0; kc < 2; kc++)
      qf[qb][kc] = *(const short8*)&Qh[(size_t)(q0 + qb * 16 + ln) * 64 + kc * 32 + hi * 8];

  const int srow = w * 16 + (lane >> 3);
  const int scol0 = ((lane & 7) * 16) ^ ((srow & 7) << 4);
  const int scol1 = ((lane & 7) * 16) ^ (((srow + 8) & 7) << 4);
  // permuted K source rows for LDS rows t0=srow, t1=srow+8:
  // p(t) = (t>>5)*32 + ((t>>2)&3)*8 + ((t>>4)&1)*4 + (t&3)
  const int t0 = srow, t1 = srow + 8;
  const int kp0 = ((t0 >> 5) << 5) | (((t0 >> 2) & 3) << 3) | (((t0 >> 4) & 1) << 2) | (t0 & 3);
  const int kp1 = ((t1 >> 5) << 5) | (((t1 >> 2) & 3) << 3) | (((t1 >> 4) & 1) << 2) | (t1 & 3);

  f32x4 acc[2][4] = {};
  f32x4 accd[2] = {};
  const short8 vones8 = {(short)0x3F80, (short)0x3F80, (short)0x3F80, (short)0x3F80,
                         (short)0x3F80, (short)0x3F80, (short)0x3F80, (short)0x3F80};

  {
    int kv = kvbase;
    gload_lds16(Kh + (size_t)(kv + kp0) * 64 + (scol0 >> 1), (char*)&Kt[0][0] + w * 2048);
    gload_lds16(Kh + (size_t)(kv + kp1) * 64 + (scol1 >> 1), (char*)&Kt[0][0] + w * 2048 + 1024);
    gload_lds16(Vh + (size_t)srow * S_ + kv + (scol0 >> 1),       (char*)&Vt[0][0] + w * 2048);
    gload_lds16(Vh + (size_t)(srow + 8) * S_ + kv + (scol1 >> 1), (char*)&Vt[0][0] + w * 2048 + 1024);
  }
  __syncthreads();

  int cur = 0;
  for (int tt = 0; tt < NT; ++tt){
    if (tt + 1 < NT){
      int kv = kvbase + (tt + 1) * 64;
      int nb = cur ^ 1;
      gload_lds16(Kh + (size_t)(kv + kp0) * 64 + (scol0 >> 1), (char*)&Kt[nb][0] + w * 2048);
      gload_lds16(Kh + (size_t)(kv + kp1) * 64 + (scol1 >> 1), (char*)&Kt[nb][0] + w * 2048 + 1024);
      gload_lds16(Vh + (size_t)srow * S_ + kv + (scol0 >> 1),       (char*)&Vt[nb][0] + w * 2048);
      gload_lds16(Vh + (size_t)(srow + 8) * S_ + kv + (scol1 >> 1), (char*)&Vt[nb][0] + w * 2048 + 1024);
    }
    const unsigned short* Kc = &Kt[cur][0];
    const unsigned short* Vc = &Vt[cur][0];

    // K fragments: qb-independent, load once (tile rows = permuted keys)
    short8 kf[4][2];
    #pragma unroll
    for (int kb = 0; kb < 4; kb++)
      #pragma unroll
      for (int kc = 0; kc < 2; kc++){
        int eb = (((kc * 64 + hi * 16) ^ ((ln & 7) << 4)) >> 1);
        kf[kb][kc] = *(const short8*)&Kc[(kb * 16 + ln) * 64 + eb];
      }

    // QK -> exp -> pack. pa8[qb][W] is a K=32 A-frag over keys W*32..W*32+31
    // in natural order (by construction of the K-row permutation).
    short8 pa8[2][2];
    #pragma unroll
    for (int qb = 0; qb < 2; qb++)
      #pragma unroll
      for (int W = 0; W < 2; W++){
        f32x4 za = {0.f, 0.f, 0.f, 0.f};
        za = mfma16(kf[2*W][0], qf[qb][0], za);
        za = mfma16(kf[2*W][1], qf[qb][1], za);
        f32x4 zb = {0.f, 0.f, 0.f, 0.f};
        zb = mfma16(kf[2*W+1][0], qf[qb][0], zb);
        zb = mfma16(kf[2*W+1][1], qf[qb][1], zb);
        unsigned a0 = __float_as_uint(fast_exp2(za[0]));
        unsigned a1 = __float_as_uint(fast_exp2(za[1]));
        unsigned a2 = __float_as_uint(fast_exp2(za[2]));
        unsigned a3 = __float_as_uint(fast_exp2(za[3]));
        unsigned b0 = __float_as_uint(fast_exp2(zb[0]));
        unsigned b1 = __float_as_uint(fast_exp2(zb[1]));
        unsigned b2 = __float_as_uint(fast_exp2(zb[2]));
        unsigned b3 = __float_as_uint(fast_exp2(zb[3]));
        union { unsigned u[4]; short8 s; } pk;
        pk.u[0] = pack_trunc(a0, a1);
        pk.u[1] = pack_trunc(a2, a3);
        pk.u[2] = pack_trunc(b0, b1);
        pk.u[3] = pack_trunc(b2, b3);
        pa8[qb][W] = pk.s;
        // denominator on the matrix pipe, SAME truncated addends (K=32)
        accd[qb] = mfma16(pa8[qb][W], vones8, accd[qb]);
      }

    // PV: K=32 MFMA; B-frag read pattern identical to QK's K-frag reads
    #pragma unroll
    for (int cb = 0; cb < 4; cb++)
      #pragma unroll
      for (int W = 0; W < 2; W++){
        int eb = (((W * 64 + hi * 16) ^ ((ln & 7) << 4)) >> 1);
        short8 vf = *(const short8*)&Vc[(cb * 16 + ln) * 64 + eb];
        acc[0][cb] = mfma16(pa8[0][W], vf, acc[0][cb]);
        acc[1][cb] = mfma16(pa8[1][W], vf, acc[1][cb]);
      }
    __syncthreads();
    cur ^= 1;
  }

  // denominator: accd rows are q=hi*4+r, all 16 cols identical -> write ln==0
  if (ln == 0){
    #pragma unroll
    for (int qb = 0; qb < 2; qb++)
      #pragma unroll
      for (int r = 0; r < 4; r++)
        pden[((size_t)(z * 2 + b) * S_ + q0 + qb * 16 + hi * 4 + r) * 16 + h] = accd[qb][r];
  }

  // numerator: direct store, h-major layout [(z*2+b)][qrow][h*64 + rr]
  const size_t rowb = (size_t)(z * 2 + b) * S_;
  #pragma unroll
  for (int qb = 0; qb < 2; qb++)
    #pragma unroll
    for (int cb = 0; cb < 4; cb++)
      #pragma unroll
      for (int r = 0; r < 4; r++){
        int qrow = q0 + qb * 16 + hi * 4 + r;
        pnum[(rowb + qrow) * 1024 + h * 64 + cb * 16 + ln] = f2b(acc[qb][cb][r]);
      }
}

// ---- kernel 5: combine partials (h-major), transpose, normalize ----------
template<int NSPLIT>
__global__ __launch_bounds__(256) void attn_reduce(const unsigned short* __restrict__ pnum,
                                                   const float* __restrict__ pden,
                                                   float* __restrict__ out){
  __shared__ float L[4 * 1056];
  const int t = threadIdx.x;
  const int row_l = t >> 6, lane = t & 63;
  const int grow = blockIdx.x * 4 + row_l;
  const int e0 = lane * 16;
  const int h = e0 >> 6;
  float den = 0.f;
  float nsum[16];
  #pragma unroll
  for (int j = 0; j < 16; j++) nsum[j] = 0.f;
  #pragma unroll
  for (int z = 0; z < NSPLIT; z++){
    const size_t prow = (size_t)z * 4096 + grow;
    den += pden[prow * 16 + h];
    #pragma unroll
    for (int c = 0; c < 2; c++){
      ushort8 nv = *(const ushort8*)&pnum[prow * 1024 + e0 + c * 8];
      #pragma unroll
      for (int k = 0; k < 8; k++) nsum[c*8 + k] += b2f(nv[k]);
    }
  }
  float rinv = 1.0f / den;
  #pragma unroll
  for (int j = 0; j < 16; j++){
    int col = e0 + j;
    L[row_l * 1056 + col + (col >> 5)] = nsum[j] * rinv;
  }
  __syncthreads();
  const int d0 = lane * 16;
  #pragma unroll
  for (int c = 0; c < 4; c++){
    f32x4 o;
    #pragma unroll
    for (int k = 0; k < 4; k++){
      int d = d0 + c * 4 + k;
      int e = ((d & 15) << 6) | (d >> 4);
      o[k] = L[row_l * 1056 + e + (e >> 5)];
    }
    *(f32x4*)&out[(size_t)grow * 1024 + d0 + c * 4] = o;
  }
}

extern "C" void kernel_launch(void* const* d_in, const int* in_sizes, int n_in,
                              void* d_out, int out_size, void* d_ws, size_t ws_size,
                              hipStream_t stream){
  const float* x  = (const float*)d_in[0];
  const float* Wq = (const float*)d_in[1];
  const float* Bq = (const float*)d_in[2];
  const float* Wk = (const float*)d_in[3];
  const float* Wv = (const float*)d_in[4];
  char* ws = (char*)d_ws;
  const size_t MB = 1024 * 1024;
  unsigned short* qatt = (unsigned short*)(ws);
  unsigned short* katt = (unsigned short*)(ws + 8 * MB);
  unsigned short* vatt = (unsigned short*)(ws + 16 * MB);
  unsigned short* xbf  = (unsigned short*)(ws + 24 * MB);
  unsigned short* wT   = (unsigned short*)(ws + 32 * MB);
  float* outp = (float*)d_out;

  prep<<<dim3(32, 32, 4), 256, 0, stream>>>(x, Wq, Wk, Wv, xbf, wT);
  qkv_gemm<<<dim3(8, 32, 3), 256, 0, stream>>>(xbf, wT, Bq, qatt, katt, vatt);

  if (ws_size >= 59 * MB){
    const int NS = 4;
    unsigned short* pnum = (unsigned short*)(ws + 24 * MB);
    float* pden = (float*)(ws + 24 * MB + (size_t)NS * 8 * MB);
    attn_fwd<NS><<<512 * NS, 256, 0, stream>>>(qatt, katt, vatt, pnum, pden);
    attn_reduce<NS><<<1024, 256, 0, stream>>>(pnum, pden, outp);
  } else if (ws_size >= 42 * MB){
    const int NS = 2;
    unsigned short* pnum = (unsigned short*)(ws + 24 * MB);
    float* pden = (float*)(ws + 24 * MB + (size_t)NS * 8 * MB);
    attn_fwd<NS><<<512 * NS, 256, 0, stream>>>(qatt, katt, vatt, pnum, pden);
    attn_reduce<NS><<<1024, 256, 0, stream>>>(pnum, pden, outp);
  } else {
    const int NS = 1;
    unsigned short* pnum = (unsigned short*)(ws + 24 * MB);
    float* pden = (float*)(ws + 24 * MB + (size_t)NS * 8 * MB);
    attn_fwd<NS><<<512 * NS, 256, 0, stream>>>(qatt, katt, vatt, pnum, pden);
    attn_reduce<NS><<<1024, 256, 0, stream>>>(pnum, pden, outp);
  }
}

// Round 17
// 97.601 us; speedup vs baseline: 1.2329x; 1.0245x over previous
//
#include <hip/hip_runtime.h>

#define B_ 2
#define S_ 2048
#define D_ 1024
#define H_ 16

typedef __attribute__((ext_vector_type(8))) short short8;
typedef __attribute__((ext_vector_type(8))) unsigned short ushort8;
typedef __attribute__((ext_vector_type(4))) short short4v;
typedef __attribute__((ext_vector_type(4))) float f32x4;

__device__ __forceinline__ unsigned short f2b(float f){
  unsigned u = __float_as_uint(f);
  u += 0x7fffu + ((u >> 16) & 1u);
  return (unsigned short)(u >> 16);
}
__device__ __forceinline__ float b2f(unsigned short b){
  return __uint_as_float(((unsigned)b) << 16);
}
__device__ __forceinline__ float fast_exp2(float x){
#if __has_builtin(__builtin_amdgcn_exp2f)
  return __builtin_amdgcn_exp2f(x);
#else
  return exp2f(x);
#endif
}
__device__ __forceinline__ unsigned pack_trunc(unsigned u_lo, unsigned u_hi){
  // dst = {hi16(u_hi), hi16(u_lo)} : bf16-truncate two f32 and pack, 1 inst
#if __has_builtin(__builtin_amdgcn_perm)
  return __builtin_amdgcn_perm(u_hi, u_lo, 0x07060302u);
#else
  return (u_lo >> 16) | (u_hi & 0xffff0000u);
#endif
}
__device__ __forceinline__ f32x4 mfma16(short8 a, short8 b, f32x4 c){
  return __builtin_amdgcn_mfma_f32_16x16x32_bf16(a, b, c, 0, 0, 0);
}
__device__ __forceinline__ void gload_lds16(const void* g, void* l){
  __builtin_amdgcn_global_load_lds((const __attribute__((address_space(1))) unsigned int*)g,
                                   (__attribute__((address_space(3))) unsigned int*)l, 16, 0, 0);
}

// ---- kernel 1: fused prep -------------------------------------------------
__global__ __launch_bounds__(256) void prep(const float* __restrict__ x,
                                            const float* __restrict__ Wq,
                                            const float* __restrict__ Wk,
                                            const float* __restrict__ Wv,
                                            unsigned short* __restrict__ xbf,
                                            unsigned short* __restrict__ wT){
  const int z = blockIdx.z;
  if (z == 3){
    int lb = blockIdx.y * 32 + blockIdx.x;
    int i = (lb * 256 + threadIdx.x) * 16;
    #pragma unroll
    for (int half = 0; half < 2; half++){
      f32x4 a = *(const f32x4*)(x + i + half * 8);
      f32x4 b = *(const f32x4*)(x + i + half * 8 + 4);
      ushort8 o;
      o[0]=f2b(a[0]); o[1]=f2b(a[1]); o[2]=f2b(a[2]); o[3]=f2b(a[3]);
      o[4]=f2b(b[0]); o[5]=f2b(b[1]); o[6]=f2b(b[2]); o[7]=f2b(b[3]);
      *(ushort8*)(xbf + i + half * 8) = o;
    }
    return;
  }
  const float* W = (z == 0) ? Wq : ((z == 1) ? Wk : Wv);
  __shared__ float tile[32][33];
  int nb = blockIdx.x * 32, kb = blockIdx.y * 32;
  int tx = threadIdx.x & 31, ty = threadIdx.x >> 5;
  #pragma unroll
  for (int it = 0; it < 4; it++){
    int row = ty + it * 8;
    tile[row][tx] = W[(size_t)(kb + row) * D_ + nb + tx];
  }
  __syncthreads();
  unsigned short* outp = wT + (size_t)z * D_ * D_;
  #pragma unroll
  for (int it = 0; it < 4; it++){
    int row = ty + it * 8;
    int n = nb + row;
    int np = ((n & 15) << 6) | (n >> 4);
    outp[(size_t)np * D_ + kb + tx] = f2b(tile[tx][row]);
  }
}

// ---- kernel 3: QKV projection GEMM (round-13-proven) ----------------------
__global__ __launch_bounds__(256) void qkv_gemm(const unsigned short* __restrict__ xbf,
                                                const unsigned short* __restrict__ wT,
                                                const float* __restrict__ Bq,
                                                unsigned short* __restrict__ qatt,
                                                unsigned short* __restrict__ katt,
                                                unsigned short* __restrict__ vatt){
  __shared__ char SM[34816];
  unsigned short* Ct = (unsigned short*)SM;
  const int proj = blockIdx.z;
  const int mbase = blockIdx.y * 128, nbase = blockIdx.x * 128;
  const unsigned short* bsrc = wT + (size_t)proj * D_ * D_;
  const int t = threadIdx.x, w = t >> 6, lane = t & 63, ln = lane & 15, hi = lane >> 4;
  const int wr = w >> 1, wc = w & 1;
  const int srow = t >> 2, scol = (t & 3) << 3;
  f32x4 acc[4][4] = {};

  #pragma unroll
  for (int i = 0; i < 2; i++){
    gload_lds16(xbf  + (size_t)(mbase + srow + i * 64) * D_ + scol, SM + w * 1024 + i * 4096);
    gload_lds16(bsrc + (size_t)(nbase + srow + i * 64) * D_ + scol, SM + 8192 + w * 1024 + i * 4096);
  }
  __syncthreads();

  int cur = 0;
  for (int ks = 0; ks < D_; ks += 32){
    if (ks + 32 < D_){
      char* nb_ = SM + (cur ^ 1) * 16384;
      #pragma unroll
      for (int i = 0; i < 2; i++){
        gload_lds16(xbf  + (size_t)(mbase + srow + i * 64) * D_ + ks + 32 + scol, nb_ + w * 1024 + i * 4096);
        gload_lds16(bsrc + (size_t)(nbase + srow + i * 64) * D_ + ks + 32 + scol, nb_ + 8192 + w * 1024 + i * 4096);
      }
    }
    const unsigned short* At = (const unsigned short*)(SM + cur * 16384);
    const unsigned short* Bt = (const unsigned short*)(SM + cur * 16384 + 8192);
    short8 af[4], bf[4];
    #pragma unroll
    for (int q = 0; q < 4; q++) af[q] = *(const short8*)&At[(wr * 64 + q * 16 + ln) * 32 + hi * 8];
    #pragma unroll
    for (int p = 0; p < 4; p++) bf[p] = *(const short8*)&Bt[(wc * 64 + p * 16 + ln) * 32 + hi * 8];
    #pragma unroll
    for (int q = 0; q < 4; q++)
      #pragma unroll
      for (int p = 0; p < 4; p++)
        acc[q][p] = mfma16(af[q], bf[p], acc[q][p]);
    __syncthreads();
    cur ^= 1;
  }

  const float qscale = 0.04508422002778011f; // log2(e)/sqrt(1024)
  const int b = mbase >> 11, ms = mbase & 2047;

  if (proj == 2){
    #pragma unroll
    for (int p = 0; p < 4; p++)
      #pragma unroll
      for (int q = 0; q < 4; q++)
        #pragma unroll
        for (int r = 0; r < 4; r++)
          Ct[(wc*64 + p*16 + ln) * 136 + wr*64 + q*16 + hi*4 + r] = f2b(acc[q][p][r]);
    __syncthreads();
    #pragma unroll
    for (int j = 0; j < 8; j++){
      int u = j * 256 + t;
      int col = u >> 4, s0 = (u & 15) * 8;
      int h = blockIdx.x * 2 + (col >> 6), r = col & 63;
      short8 v = *(const short8*)&Ct[col * 136 + s0];
      *(short8*)&vatt[((size_t)(b*16 + h) * 64 + r) * 2048 + ms + s0] = v;
    }
  } else {
    const int hglob = blockIdx.x * 2 + wc;
    #pragma unroll
    for (int p = 0; p < 4; p++){
      float bqv = (proj == 0) ? Bq[(p*16 + ln)*16 + hglob] : 0.f;
      #pragma unroll
      for (int q = 0; q < 4; q++)
        #pragma unroll
        for (int r = 0; r < 4; r++){
          float v = acc[q][p][r];
          if (proj == 0) v = (v + bqv) * qscale;
          Ct[(wr*64 + q*16 + hi*4 + r) * 136 + wc*64 + p*16 + ln] = f2b(v);
        }
    }
    __syncthreads();
    unsigned short* dstb = (proj == 0) ? qatt : katt;
    #pragma unroll
    for (int j = 0; j < 8; j++){
      int u = j * 256 + t;
      int hl = u >> 10, rem = u & 1023, sl = rem >> 3, r0 = (rem & 7) * 8;
      int h = blockIdx.x * 2 + hl;
      short8 v = *(const short8*)&Ct[sl * 136 + hl*64 + r0];
      *(short8*)&dstb[((size_t)(b*16 + h) * 2048 + ms + sl) * 64 + r0] = v;
    }
  }
}

// ---- kernel 4: attention — K=32 PV (round-16 math) + SINGLE-buffer K/V ----
// 16KB LDS -> capacity 8 blocks/CU (wave-slot-capped, 32 waves/CU = HW max);
// NS=4 gives exactly 8 blocks/CU of work -> all resident, single scheduling
// round, no tail. T5 setprio around compute (8 independent blocks/CU = the
// phase-diverse regime where it pays, m191). Sync shape = round-14-proven.
template<int NS>
__global__ __launch_bounds__(256) void attn_fwd(const unsigned short* __restrict__ qatt,
                                                const unsigned short* __restrict__ katt,
                                                const unsigned short* __restrict__ vatt,
                                                unsigned short* __restrict__ pnum,
                                                float* __restrict__ pden){
  __shared__ unsigned short Kt[64 * 64];
  __shared__ unsigned short Vt[64 * 64];
  const int t = threadIdx.x, w = t >> 6, lane = t & 63, ln = lane & 15, hi = lane >> 4;
  const int bid = blockIdx.x;
  const int bpx = (512 * NS) / 8;
  const int L = (bid & 7) * bpx + (bid >> 3);
  const int bh = L / (16 * NS);
  const int rem = L % (16 * NS);
  const int z = rem >> 4, qc = rem & 15;
  const int b = bh >> 4, h = bh & 15;
  const int q0 = qc * 128 + w * 32;
  const int kvbase = z * (S_ / NS);
  const int NT = (S_ / NS) / 64;
  const unsigned short* Qh = qatt + (size_t)bh * S_ * 64;
  const unsigned short* Kh = katt + (size_t)bh * S_ * 64;
  const unsigned short* Vh = vatt + (size_t)bh * 64 * S_;

  short8 qf[2][2];
  #pragma unroll
  for (int qb = 0; qb < 2; qb++)
    #pragma unroll
    for (int kc = 0; kc < 2; kc++)
      qf[qb][kc] = *(const short8*)&Qh[(size_t)(q0 + qb * 16 + ln) * 64 + kc * 32 + hi * 8];

  const int srow = w * 16 + (lane >> 3);
  const int scol0 = ((lane & 7) * 16) ^ ((srow & 7) << 4);
  const int scol1 = ((lane & 7) * 16) ^ (((srow + 8) & 7) << 4);
  // permuted K source rows for LDS rows t0=srow, t1=srow+8:
  // p(t) = (t>>5)*32 + ((t>>2)&3)*8 + ((t>>4)&1)*4 + (t&3)
  const int t0 = srow, t1 = srow + 8;
  const int kp0 = ((t0 >> 5) << 5) | (((t0 >> 2) & 3) << 3) | (((t0 >> 4) & 1) << 2) | (t0 & 3);
  const int kp1 = ((t1 >> 5) << 5) | (((t1 >> 2) & 3) << 3) | (((t1 >> 4) & 1) << 2) | (t1 & 3);

  f32x4 acc[2][4] = {};
  f32x4 accd[2] = {};
  const short8 vones8 = {(short)0x3F80, (short)0x3F80, (short)0x3F80, (short)0x3F80,
                         (short)0x3F80, (short)0x3F80, (short)0x3F80, (short)0x3F80};

  for (int tt = 0; tt < NT; ++tt){
    const int kv = kvbase + tt * 64;
    gload_lds16(Kh + (size_t)(kv + kp0) * 64 + (scol0 >> 1), (char*)Kt + w * 2048);
    gload_lds16(Kh + (size_t)(kv + kp1) * 64 + (scol1 >> 1), (char*)Kt + w * 2048 + 1024);
    gload_lds16(Vh + (size_t)srow * S_ + kv + (scol0 >> 1),       (char*)Vt + w * 2048);
    gload_lds16(Vh + (size_t)(srow + 8) * S_ + kv + (scol1 >> 1), (char*)Vt + w * 2048 + 1024);
    __syncthreads();   // drains vmcnt -> staged tile visible to all waves

    __builtin_amdgcn_s_setprio(1);
    // K fragments: qb-independent, load once (tile rows = permuted keys)
    short8 kf[4][2];
    #pragma unroll
    for (int kb = 0; kb < 4; kb++)
      #pragma unroll
      for (int kc = 0; kc < 2; kc++){
        int eb = (((kc * 64 + hi * 16) ^ ((ln & 7) << 4)) >> 1);
        kf[kb][kc] = *(const short8*)&Kt[(kb * 16 + ln) * 64 + eb];
      }

    // QK -> exp -> pack. pa8[qb][W] is a K=32 A-frag over keys W*32..W*32+31
    // in natural order (by construction of the K-row permutation).
    short8 pa8[2][2];
    #pragma unroll
    for (int qb = 0; qb < 2; qb++)
      #pragma unroll
      for (int W = 0; W < 2; W++){
        f32x4 za = {0.f, 0.f, 0.f, 0.f};
        za = mfma16(kf[2*W][0], qf[qb][0], za);
        za = mfma16(kf[2*W][1], qf[qb][1], za);
        f32x4 zb = {0.f, 0.f, 0.f, 0.f};
        zb = mfma16(kf[2*W+1][0], qf[qb][0], zb);
        zb = mfma16(kf[2*W+1][1], qf[qb][1], zb);
        unsigned a0 = __float_as_uint(fast_exp2(za[0]));
        unsigned a1 = __float_as_uint(fast_exp2(za[1]));
        unsigned a2 = __float_as_uint(fast_exp2(za[2]));
        unsigned a3 = __float_as_uint(fast_exp2(za[3]));
        unsigned b0 = __float_as_uint(fast_exp2(zb[0]));
        unsigned b1 = __float_as_uint(fast_exp2(zb[1]));
        unsigned b2 = __float_as_uint(fast_exp2(zb[2]));
        unsigned b3 = __float_as_uint(fast_exp2(zb[3]));
        union { unsigned u[4]; short8 s; } pk;
        pk.u[0] = pack_trunc(a0, a1);
        pk.u[1] = pack_trunc(a2, a3);
        pk.u[2] = pack_trunc(b0, b1);
        pk.u[3] = pack_trunc(b2, b3);
        pa8[qb][W] = pk.s;
        // denominator on the matrix pipe, SAME truncated addends (K=32)
        accd[qb] = mfma16(pa8[qb][W], vones8, accd[qb]);
      }

    // PV: K=32 MFMA; B-frag read pattern identical to QK's K-frag reads
    #pragma unroll
    for (int cb = 0; cb < 4; cb++)
      #pragma unroll
      for (int W = 0; W < 2; W++){
        int eb = (((W * 64 + hi * 16) ^ ((ln & 7) << 4)) >> 1);
        short8 vf = *(const short8*)&Vt[(cb * 16 + ln) * 64 + eb];
        acc[0][cb] = mfma16(pa8[0][W], vf, acc[0][cb]);
        acc[1][cb] = mfma16(pa8[1][W], vf, acc[1][cb]);
      }
    __builtin_amdgcn_s_setprio(0);
    __syncthreads();   // all reads done before next tile overwrites buffer
  }

  // denominator: accd rows are q=hi*4+r, all 16 cols identical -> write ln==0
  if (ln == 0){
    #pragma unroll
    for (int qb = 0; qb < 2; qb++)
      #pragma unroll
      for (int r = 0; r < 4; r++)
        pden[((size_t)(z * 2 + b) * S_ + q0 + qb * 16 + hi * 4 + r) * 16 + h] = accd[qb][r];
  }

  // numerator: direct store, h-major layout [(z*2+b)][qrow][h*64 + rr]
  const size_t rowb = (size_t)(z * 2 + b) * S_;
  #pragma unroll
  for (int qb = 0; qb < 2; qb++)
    #pragma unroll
    for (int cb = 0; cb < 4; cb++)
      #pragma unroll
      for (int r = 0; r < 4; r++){
        int qrow = q0 + qb * 16 + hi * 4 + r;
        pnum[(rowb + qrow) * 1024 + h * 64 + cb * 16 + ln] = f2b(acc[qb][cb][r]);
      }
}

// ---- kernel 5: combine partials (h-major), transpose, normalize ----------
template<int NSPLIT>
__global__ __launch_bounds__(256) void attn_reduce(const unsigned short* __restrict__ pnum,
                                                   const float* __restrict__ pden,
                                                   float* __restrict__ out){
  __shared__ float L[4 * 1056];
  const int t = threadIdx.x;
  const int row_l = t >> 6, lane = t & 63;
  const int grow = blockIdx.x * 4 + row_l;
  const int e0 = lane * 16;
  const int h = e0 >> 6;
  float den = 0.f;
  float nsum[16];
  #pragma unroll
  for (int j = 0; j < 16; j++) nsum[j] = 0.f;
  #pragma unroll
  for (int z = 0; z < NSPLIT; z++){
    const size_t prow = (size_t)z * 4096 + grow;
    den += pden[prow * 16 + h];
    #pragma unroll
    for (int c = 0; c < 2; c++){
      ushort8 nv = *(const ushort8*)&pnum[prow * 1024 + e0 + c * 8];
      #pragma unroll
      for (int k = 0; k < 8; k++) nsum[c*8 + k] += b2f(nv[k]);
    }
  }
  float rinv = 1.0f / den;
  #pragma unroll
  for (int j = 0; j < 16; j++){
    int col = e0 + j;
    L[row_l * 1056 + col + (col >> 5)] = nsum[j] * rinv;
  }
  __syncthreads();
  const int d0 = lane * 16;
  #pragma unroll
  for (int c = 0; c < 4; c++){
    f32x4 o;
    #pragma unroll
    for (int k = 0; k < 4; k++){
      int d = d0 + c * 4 + k;
      int e = ((d & 15) << 6) | (d >> 4);
      o[k] = L[row_l * 1056 + e + (e >> 5)];
    }
    *(f32x4*)&out[(size_t)grow * 1024 + d0 + c * 4] = o;
  }
}

extern "C" void kernel_launch(void* const* d_in, const int* in_sizes, int n_in,
                              void* d_out, int out_size, void* d_ws, size_t ws_size,
                              hipStream_t stream){
  const float* x  = (const float*)d_in[0];
  const float* Wq = (const float*)d_in[1];
  const float* Bq = (const float*)d_in[2];
  const float* Wk = (const float*)d_in[3];
  const float* Wv = (const float*)d_in[4];
  char* ws = (char*)d_ws;
  const size_t MB = 1024 * 1024;
  unsigned short* qatt = (unsigned short*)(ws);
  unsigned short* katt = (unsigned short*)(ws + 8 * MB);
  unsigned short* vatt = (unsigned short*)(ws + 16 * MB);
  unsigned short* xbf  = (unsigned short*)(ws + 24 * MB);
  unsigned short* wT   = (unsigned short*)(ws + 32 * MB);
  float* outp = (float*)d_out;

  prep<<<dim3(32, 32, 4), 256, 0, stream>>>(x, Wq, Wk, Wv, xbf, wT);
  qkv_gemm<<<dim3(8, 32, 3), 256, 0, stream>>>(xbf, wT, Bq, qatt, katt, vatt);

  if (ws_size >= 59 * MB){
    const int NS = 4;
    unsigned short* pnum = (unsigned short*)(ws + 24 * MB);
    float* pden = (float*)(ws + 24 * MB + (size_t)NS * 8 * MB);
    attn_fwd<NS><<<512 * NS, 256, 0, stream>>>(qatt, katt, vatt, pnum, pden);
    attn_reduce<NS><<<1024, 256, 0, stream>>>(pnum, pden, outp);
  } else if (ws_size >= 42 * MB){
    const int NS = 2;
    unsigned short* pnum = (unsigned short*)(ws + 24 * MB);
    float* pden = (float*)(ws + 24 * MB + (size_t)NS * 8 * MB);
    attn_fwd<NS><<<512 * NS, 256, 0, stream>>>(qatt, katt, vatt, pnum, pden);
    attn_reduce<NS><<<1024, 256, 0, stream>>>(pnum, pden, outp);
  } else {
    const int NS = 1;
    unsigned short* pnum = (unsigned short*)(ws + 24 * MB);
    float* pden = (float*)(ws + 24 * MB + (size_t)NS * 8 * MB);
    attn_fwd<NS><<<512 * NS, 256, 0, stream>>>(qatt, katt, vatt, pnum, pden);
    attn_reduce<NS><<<1024, 256, 0, stream>>>(pnum, pden, outp);
  }
}